// Round 15
// baseline (124.985 us; speedup 1.0000x reference)
//
#include <hip/hip_runtime.h>
#include <hip/hip_bf16.h>

// ConvSelfAttn: B=8, N=4096, C=64, d=8. FP32 I/O.
// R28: R27 compile fix only. R27 failed because AREGS/BREGS (macro packs)
// count as ONE argument at invocation; expansion happens after parameter
// matching. Fix: XC(M, ...) indirection — XC's args are fully expanded
// (AREGS -> 10 names) BEFORE substitution into M(__VA_ARGS__).
// Experiment unchanged: inline-asm K/V register double-buffer, 20 named
// half8 scalars (nothing address-taken), counted s_waitcnt vmcnt(10) with
// all 10 buffer regs tied "+v" (SSA-enforced ordering, live ranges cover
// in-flight loads), peeled tail (exact counts; all loop VMEM is our asm).
// Baseline otherwise = R24 (total 120.4us best; attn 51.2).
// Verify: VGPR ~145-165 (dbuf live). Tripwires: WRITE ~8.2MB, absmax 0.03125.

#define BB 8
#define NN 4096
#define CC 64
#define PSTRIDE 72
#define LOG2E 1.44269504088896f

typedef _Float16 f16;
typedef _Float16 half8 __attribute__((ext_vector_type(8)));
typedef _Float16 half4 __attribute__((ext_vector_type(4)));
typedef __fp16 fp16x2 __attribute__((ext_vector_type(2)));
typedef float floatx4 __attribute__((ext_vector_type(4)));

static __device__ inline half4 pack4(float a, float b, float c, float d) {
    fp16x2 lo = __builtin_amdgcn_cvt_pkrtz(a, b);
    fp16x2 hi = __builtin_amdgcn_cvt_pkrtz(c, d);
    unsigned int lou = __builtin_bit_cast(unsigned int, lo);
    unsigned int hiu = __builtin_bit_cast(unsigned int, hi);
    unsigned long long packed = (unsigned long long)lou | ((unsigned long long)hiu << 32);
    return __builtin_bit_cast(half4, packed);
}

// ws layouts (halfs):
//   Qh [B*N][8]                          Q pre-scaled by log2e
//   Kf [B][128 pair][64 lane][8]         pair-interleaved QK A-frags
//   Vf [B][128 pair][4 ct][64 lane][8]   16x16x16 PV A-frags
//   qn2 [B*N] f32 | Mkb [512] f32 (per-proj-block key-norm max, no init)

// ---------------- fused projection + fragment repack + norms + key-max ----------------
__global__ __launch_bounds__(256) void proj_all_kernel(
    const float* __restrict__ x,
    const float* __restrict__ wq, const float* __restrict__ bq,
    const float* __restrict__ wk, const float* __restrict__ bk,
    const float* __restrict__ wv, const float* __restrict__ bv,
    f16* __restrict__ Qh, f16* __restrict__ Kf, f16* __restrict__ Vf,
    float* __restrict__ qn2, float* __restrict__ Mkb)
{
    __shared__ alignas(16) f16 Ws[80][PSTRIDE];  // rows 0-63=V, 64-71=Q, 72-79=K
    __shared__ float Bs[80];
    __shared__ alignas(16) f16 Vst[64][68];      // TRANSPOSED: [ch][pixel], pitch 68
    __shared__ alignas(16) f16 Ks[64][12];       // [pixel][ch]
    __shared__ float redK[4];
    const int tid = threadIdx.x;

    for (int i4 = tid; i4 < 1024; i4 += 256) {   // 4 iters
        const int i = i4 * 4;
        const int cin = i >> 6, cout = i & 63;
        const float4 w = *(const float4*)(wv + i);
        Ws[cout + 0][cin] = (f16)w.x;
        Ws[cout + 1][cin] = (f16)w.y;
        Ws[cout + 2][cin] = (f16)w.z;
        Ws[cout + 3][cin] = (f16)w.w;
    }
    if (tid < 128) {                              // wq/wk: i = cin*8+c
        const int i = tid * 4;
        const int cin = i >> 3, c = i & 7;
        const float4 a = *(const float4*)(wq + i);
        const float4 k = *(const float4*)(wk + i);
        Ws[64 + c + 0][cin] = (f16)(a.x * LOG2E);
        Ws[64 + c + 1][cin] = (f16)(a.y * LOG2E);
        Ws[64 + c + 2][cin] = (f16)(a.z * LOG2E);
        Ws[64 + c + 3][cin] = (f16)(a.w * LOG2E);
        Ws[72 + c + 0][cin] = (f16)k.x;
        Ws[72 + c + 1][cin] = (f16)k.y;
        Ws[72 + c + 2][cin] = (f16)k.z;
        Ws[72 + c + 3][cin] = (f16)k.w;
    }
    if (tid < 80)
        Bs[tid] = (tid < 64) ? bv[tid]
                : (tid < 72 ? bq[tid - 64] * LOG2E : bk[tid - 72]);
    __syncthreads();

    const int wave = tid >> 6, lane = tid & 63;
    const int quad = lane >> 4, n16 = lane & 15;
    const long pb = (long)blockIdx.x * 64;
    const long p0 = pb + wave * 16;
    const int  b   = (int)(pb >> 12);
    const int  nnb = (int)(pb & 4095);

    half8 ax[2];
#pragma unroll
    for (int kh = 0; kh < 2; ++kh) {
        const float* xp = x + (p0 + n16) * 64 + kh * 32 + quad * 8;
        float4 x1 = *(const float4*)xp;
        float4 x2 = *(const float4*)(xp + 4);
        ax[kh][0] = (f16)x1.x; ax[kh][1] = (f16)x1.y;
        ax[kh][2] = (f16)x1.z; ax[kh][3] = (f16)x1.w;
        ax[kh][4] = (f16)x2.x; ax[kh][5] = (f16)x2.y;
        ax[kh][6] = (f16)x2.z; ax[kh][7] = (f16)x2.w;
    }

#pragma unroll
    for (int ct = 0; ct < 5; ++ct) {
        const int cout = (ct < 4) ? ct * 16 + n16 : 64 + n16;
        const float bias = Bs[cout];
        half8 b0 = *(const half8*)(&Ws[cout][quad * 8]);
        half8 b1 = *(const half8*)(&Ws[cout][32 + quad * 8]);
        floatx4 acc = {bias, bias, bias, bias};
        acc = __builtin_amdgcn_mfma_f32_16x16x32_f16(ax[0], b0, acc, 0, 0, 0);
        acc = __builtin_amdgcn_mfma_f32_16x16x32_f16(ax[1], b1, acc, 0, 0, 0);
        if (ct < 4) {
            half4 vp = {(f16)acc[0], (f16)acc[1], (f16)acc[2], (f16)acc[3]};
            *(half4*)(&Vst[ct * 16 + n16][wave * 16 + quad * 4]) = vp;
        } else {
            float n2[4];
#pragma unroll
            for (int r = 0; r < 4; ++r) n2[r] = acc[r] * acc[r];
#pragma unroll
            for (int d = 1; d < 8; d <<= 1)
#pragma unroll
                for (int r = 0; r < 4; ++r) n2[r] += __shfl_xor(n2[r], d, 64);
            if (n16 == 0) {
#pragma unroll
                for (int r = 0; r < 4; ++r) qn2[p0 + quad * 4 + r] = n2[r];
            }
            float km = fmaxf(fmaxf(n2[0], n2[1]), fmaxf(n2[2], n2[3]));
            km = fmaxf(km, __shfl_xor(km, 16, 64));
            km = fmaxf(km, __shfl_xor(km, 32, 64));
            if (n16 == 8) redK[wave] = km;
            if (n16 < 8) {
                f16* dst = Qh + (p0 + quad * 4) * 8 + n16;
#pragma unroll
                for (int r = 0; r < 4; ++r) dst[r * 8] = (f16)acc[r];
            } else {
#pragma unroll
                for (int r = 0; r < 4; ++r)
                    Ks[wave * 16 + quad * 4 + r][n16 - 8] = (f16)acc[r];
            }
        }
    }
    __syncthreads();

    if (tid == 0) {
        float m = fmaxf(fmaxf(redK[0], redK[1]), fmaxf(redK[2], redK[3]));
        Mkb[blockIdx.x] = m;
    }

#pragma unroll
    for (int u = 0; u < 2; ++u) {
        const int tt = wave * 2 + u;
        const int kb = tt >> 2, ct = tt & 3;
        half4 lo = *(const half4*)(&Vst[ct * 16 + n16][kb * 32 + quad * 4]);
        half4 hi = *(const half4*)(&Vst[ct * 16 + n16][kb * 32 + 16 + quad * 4]);
        half8 v = {lo[0], lo[1], lo[2], lo[3], hi[0], hi[1], hi[2], hi[3]};
        const size_t kbg = (size_t)b * 128 + (nnb >> 5) + kb;
        *(half8*)(Vf + (kbg * 4 + ct) * 512 + lane * 8) = v;
    }
    if (wave < 2) {
        half8 kp = {0, 0, 0, 0, 0, 0, 0, 0};
#pragma unroll
        for (int e = 0; e < 2; ++e) {
            const int t = wave * 2 + e;
            if (quad < 2) {
                half4 kd = *(const half4*)(&Ks[t * 16 + n16][quad * 4]);
                kp[e * 4 + 0] = kd[0]; kp[e * 4 + 1] = kd[1];
                kp[e * 4 + 2] = kd[2]; kp[e * 4 + 3] = kd[3];
            } else if (quad == 2) {
                kp[e * 4 + 0] = (f16)1.f;  // mf ones channel
            }
        }
        const size_t kpg = (size_t)b * 128 + (nnb >> 5) + wave;
        *(half8*)(Kf + kpg * 512 + lane * 8) = kp;
    }
}

// ---------------- flash attention: asm K/V dbuf, named-scalar registers ----------------
// grid B*128 = 1024 x 256 thr; wave = ks (0..3): keys [ks*1024,+1024), 16
// tiles of 64 keys. All loop VMEM = asm volatile; counted vmcnt with "+v"
// tied buffer operands (SSA-enforced ordering). P never touches LDS.

// macro-call indirection: XC's args are fully expanded (AREGS -> 10 names)
// BEFORE substitution into M(__VA_ARGS__), so M sees all 11 arguments.
#define XC(M, ...) M(__VA_ARGS__)

// issue the 10 loads (2 K + 8 V) of key-tile ITN into named regs
#define ISSUE_TILE(ITN, K0, K1, V00, V01, V02, V03, V10, V11, V12, V13) do { \
    const char* kb_  = kfb + (size_t)(ITN) * 2048;                            \
    const char* vb0_ = vfb + (size_t)(ITN) * 8192;                            \
    const char* vb1_ = vb0_ + 4096;                                           \
    __asm__ volatile("global_load_dwordx4 %0, %1, off"             : "=&v"(K0)  : "v"(kb_)  : "memory"); \
    __asm__ volatile("global_load_dwordx4 %0, %1, off offset:1024" : "=&v"(K1)  : "v"(kb_)  : "memory"); \
    __asm__ volatile("global_load_dwordx4 %0, %1, off"             : "=&v"(V00) : "v"(vb0_) : "memory"); \
    __asm__ volatile("global_load_dwordx4 %0, %1, off offset:1024" : "=&v"(V01) : "v"(vb0_) : "memory"); \
    __asm__ volatile("global_load_dwordx4 %0, %1, off offset:2048" : "=&v"(V02) : "v"(vb0_) : "memory"); \
    __asm__ volatile("global_load_dwordx4 %0, %1, off offset:3072" : "=&v"(V03) : "v"(vb0_) : "memory"); \
    __asm__ volatile("global_load_dwordx4 %0, %1, off"             : "=&v"(V10) : "v"(vb1_) : "memory"); \
    __asm__ volatile("global_load_dwordx4 %0, %1, off offset:1024" : "=&v"(V11) : "v"(vb1_) : "memory"); \
    __asm__ volatile("global_load_dwordx4 %0, %1, off offset:2048" : "=&v"(V12) : "v"(vb1_) : "memory"); \
    __asm__ volatile("global_load_dwordx4 %0, %1, off offset:3072" : "=&v"(V13) : "v"(vb1_) : "memory"); \
} while (0)

// counted wait; ties all 10 buffer regs so consumers depend on THIS asm's
// defs (unhoistable) and live ranges cover the in-flight loads.
#define WAIT_TILE(CNT, K0, K1, V00, V01, V02, V03, V10, V11, V12, V13)        \
    __asm__ volatile("s_waitcnt vmcnt(" CNT ")"                               \
        : "+v"(K0), "+v"(K1), "+v"(V00), "+v"(V01), "+v"(V02), "+v"(V03),     \
          "+v"(V10), "+v"(V11), "+v"(V12), "+v"(V13) :: "memory")

// per-16-key-tile softmax + PV (R16 body, named V regs)
#define SM_PV(SF, HI, VA, VB, VC, VD) do {                                    \
    float p0_ = __builtin_exp2f((SF)[0]);                                     \
    float p1_ = __builtin_exp2f((SF)[1]);                                     \
    float p2_ = __builtin_exp2f((SF)[2]);                                     \
    float p3_ = __builtin_exp2f((SF)[3]);                                     \
    l_loc[qt2] += (p0_ + p1_) + (p2_ + p3_);                                  \
    half4 pk_ = pack4(p0_, p1_, p2_, p3_);                                    \
    half4 va_;                                                                \
    va_ = (HI) ? __builtin_shufflevector(VA, VA, 4, 5, 6, 7)                  \
               : __builtin_shufflevector(VA, VA, 0, 1, 2, 3);                 \
    oacc[qt2][0] = __builtin_amdgcn_mfma_f32_16x16x16f16(va_, pk_, oacc[qt2][0], 0, 0, 0); \
    va_ = (HI) ? __builtin_shufflevector(VB, VB, 4, 5, 6, 7)                  \
               : __builtin_shufflevector(VB, VB, 0, 1, 2, 3);                 \
    oacc[qt2][1] = __builtin_amdgcn_mfma_f32_16x16x16f16(va_, pk_, oacc[qt2][1], 0, 0, 0); \
    va_ = (HI) ? __builtin_shufflevector(VC, VC, 4, 5, 6, 7)                  \
               : __builtin_shufflevector(VC, VC, 0, 1, 2, 3);                 \
    oacc[qt2][2] = __builtin_amdgcn_mfma_f32_16x16x16f16(va_, pk_, oacc[qt2][2], 0, 0, 0); \
    va_ = (HI) ? __builtin_shufflevector(VD, VD, 4, 5, 6, 7)                  \
               : __builtin_shufflevector(VD, VD, 0, 1, 2, 3);                 \
    oacc[qt2][3] = __builtin_amdgcn_mfma_f32_16x16x16f16(va_, pk_, oacc[qt2][3], 0, 0, 0); \
} while (0)

#define COMPUTE_TILE(K0, K1, V00, V01, V02, V03, V10, V11, V12, V13) do {     \
    half4 ak0_ = __builtin_shufflevector(K0, K0, 0, 1, 2, 3);                 \
    half4 ak1_ = __builtin_shufflevector(K0, K0, 4, 5, 6, 7);                 \
    half4 ak2_ = __builtin_shufflevector(K1, K1, 0, 1, 2, 3);                 \
    half4 ak3_ = __builtin_shufflevector(K1, K1, 4, 5, 6, 7);                 \
    _Pragma("unroll")                                                         \
    for (int qt2 = 0; qt2 < 2; ++qt2) {                                       \
        floatx4 sf0_ = __builtin_amdgcn_mfma_f32_16x16x16f16(ak0_, bq4[qt2], zero4, 0, 0, 0); \
        floatx4 sf1_ = __builtin_amdgcn_mfma_f32_16x16x16f16(ak1_, bq4[qt2], zero4, 0, 0, 0); \
        floatx4 sf2_ = __builtin_amdgcn_mfma_f32_16x16x16f16(ak2_, bq4[qt2], zero4, 0, 0, 0); \
        floatx4 sf3_ = __builtin_amdgcn_mfma_f32_16x16x16f16(ak3_, bq4[qt2], zero4, 0, 0, 0); \
        SM_PV(sf0_, 0, V00, V01, V02, V03);                                   \
        SM_PV(sf1_, 1, V00, V01, V02, V03);                                   \
        SM_PV(sf2_, 0, V10, V11, V12, V13);                                   \
        SM_PV(sf3_, 1, V10, V11, V12, V13);                                   \
    }                                                                         \
} while (0)

#define AREGS kA0, kA1, vA00, vA01, vA02, vA03, vA10, vA11, vA12, vA13
#define BREGS kB0, kB1, vB00, vB01, vB02, vB03, vB10, vB11, vB12, vB13

__global__ __launch_bounds__(256, 3) void attn_kernel(
    const f16* __restrict__ Qh, const f16* __restrict__ Kf,
    const f16* __restrict__ Vf,
    const float* __restrict__ qn2, const float* __restrict__ Mkb,
    const float* __restrict__ x, const float* __restrict__ gptr,
    float* __restrict__ out)
{
    // smem: Obuf only (f32, stride 20, 3 partial ks x 2 qt2 x 64 lanes x 16ch)
    __shared__ alignas(16) char smem[30720];
    __shared__ float Ls[4][2][16];
    float* Obuf = (float*)smem;

    const int tid  = threadIdx.x;
    const int wave = tid >> 6, lane = tid & 63;
    const int quad = lane >> 4, n16 = lane & 15;
    const int ks = wave;

    const int b  = blockIdx.x & 7;
    const int qt = blockIdx.x >> 3;               // 0..127 (32-query tile)
    const size_t bN = (size_t)b * NN;

    // per-batch key-norm max: reduce this batch's 64 per-proj-block slots
    float mk2;
    {
        float m = Mkb[b * 64 + lane];
        m = fmaxf(m, __shfl_xor(m, 1, 64));
        m = fmaxf(m, __shfl_xor(m, 2, 64));
        m = fmaxf(m, __shfl_xor(m, 4, 64));
        m = fmaxf(m, __shfl_xor(m, 8, 64));
        m = fmaxf(m, __shfl_xor(m, 16, 64));
        m = fmaxf(m, __shfl_xor(m, 32, 64));
        mk2 = m;
    }

    // Q B-frags: quads 0-1 = Q data; quad2 = {-mf,0,0,0}; quad3 = 0.
    half4 bq4[2];
#pragma unroll
    for (int qt2 = 0; qt2 < 2; ++qt2) {
        const int q = qt * 32 + qt2 * 16 + n16;
        const float mf = __builtin_sqrtf(qn2[bN + q] * mk2) - 12.0f;
        half4 v = {0, 0, 0, 0};
        if (quad < 2)
            v = *(const half4*)(Qh + (bN + q) * 8 + quad * 4);
        else if (quad == 2)
            v[0] = (f16)(-mf);
        bq4[qt2] = v;
    }

    floatx4 oacc[2][4];
#pragma unroll
    for (int qt2 = 0; qt2 < 2; ++qt2)
#pragma unroll
        for (int ct = 0; ct < 4; ++ct) oacc[qt2][ct] = (floatx4){0.f, 0.f, 0.f, 0.f};
    float l_loc[2] = {0.f, 0.f};

    const char* kfb = (const char*)(Kf + ((size_t)b * 128 + ks * 32) * 512 + lane * 8);
    const char* vfb = (const char*)(Vf + ((size_t)b * 128 + ks * 32) * 2048 + lane * 8);
    const floatx4 zero4 = {0.f, 0.f, 0.f, 0.f};

    // 20 NAMED buffer registers (no arrays, nothing address-taken)
    half8 kA0, kA1, vA00, vA01, vA02, vA03, vA10, vA11, vA12, vA13;
    half8 kB0, kB1, vB00, vB01, vB02, vB03, vB10, vB11, vB12, vB13;

    XC(ISSUE_TILE, 0, AREGS);
    for (int i2 = 0; i2 < 7; ++i2) {
        XC(ISSUE_TILE, 2 * i2 + 1, BREGS);
        XC(WAIT_TILE, "10", AREGS);      // A's 10 done; B's 10 in flight
        XC(COMPUTE_TILE, AREGS);         // tile 2*i2
        XC(ISSUE_TILE, 2 * i2 + 2, AREGS);
        XC(WAIT_TILE, "10", BREGS);
        XC(COMPUTE_TILE, BREGS);         // tile 2*i2+1
    }
    XC(ISSUE_TILE, 15, BREGS);
    XC(WAIT_TILE, "10", AREGS);
    XC(COMPUTE_TILE, AREGS);             // tile 14
    XC(WAIT_TILE, "0", BREGS);
    XC(COMPUTE_TILE, BREGS);             // tile 15 (nothing left in flight)

    float l_run[2];
#pragma unroll
    for (int qt2 = 0; qt2 < 2; ++qt2) {
        float l = l_loc[qt2];
        l += __shfl_xor(l, 16, 64);
        l += __shfl_xor(l, 32, 64);
        l_run[qt2] = l;
    }

    __syncthreads();   // Obuf combine (f32, stride 20)
    if (ks > 0) {
#pragma unroll
        for (int qt2 = 0; qt2 < 2; ++qt2) {
            if (quad == 0) Ls[ks][qt2][n16] = l_run[qt2];
            float* ob = Obuf + (size_t)(((ks - 1) * 2 + qt2) * 64 + lane) * 20;
#pragma unroll
            for (int ct = 0; ct < 4; ++ct)
                *(floatx4*)(ob + ct * 4) = oacc[qt2][ct];
        }
    }
    __syncthreads();
    if (ks == 0) {
        const float g = gptr[0];
#pragma unroll
        for (int qt2 = 0; qt2 < 2; ++qt2) {
            float l = l_run[qt2];
            float o[16];
#pragma unroll
            for (int ct = 0; ct < 4; ++ct)
#pragma unroll
                for (int r = 0; r < 4; ++r) o[ct * 4 + r] = oacc[qt2][ct][r];
#pragma unroll
            for (int p = 1; p < 4; ++p) {
                l += Ls[p][qt2][n16];
                const float* ob = Obuf + (size_t)(((p - 1) * 2 + qt2) * 64 + lane) * 20;
#pragma unroll
                for (int ct = 0; ct < 4; ++ct) {
                    floatx4 t = *(const floatx4*)(ob + ct * 4);
                    o[ct * 4 + 0] += t[0]; o[ct * 4 + 1] += t[1];
                    o[ct * 4 + 2] += t[2]; o[ct * 4 + 3] += t[3];
                }
            }
            const float scale = g / l;
            const int q = qt * 32 + qt2 * 16 + n16;
#pragma unroll
            for (int ct = 0; ct < 4; ++ct) {
                const size_t idx = (bN + q) * CC + ct * 16 + quad * 4;
                float4 xr = *(const float4*)(x + idx);
                float4 res;
                res.x = o[ct * 4 + 0] * scale + xr.x;
                res.y = o[ct * 4 + 1] * scale + xr.y;
                res.z = o[ct * 4 + 2] * scale + xr.z;
                res.w = o[ct * 4 + 3] * scale + xr.w;
                *(float4*)(out + idx) = res;
            }
        }
    }
}

extern "C" void kernel_launch(void* const* d_in, const int* in_sizes, int n_in,
                              void* d_out, int out_size, void* d_ws, size_t ws_size,
                              hipStream_t stream) {
    const float* x     = (const float*)d_in[0];
    const float* wq    = (const float*)d_in[1];
    const float* bq    = (const float*)d_in[2];
    const float* wk    = (const float*)d_in[3];
    const float* bk    = (const float*)d_in[4];
    const float* wv    = (const float*)d_in[5];
    const float* bv    = (const float*)d_in[6];
    const float* gamma = (const float*)d_in[7];
    float* out = (float*)d_out;

    // ws: Qh 512KB | Kf 1MB | Vf 4MB | qn2 128KB | Mkb 2KB (per-block maxima)
    f16* Qh = (f16*)d_ws;
    f16* Kf = Qh + (size_t)BB * NN * 8;
    f16* Vf = Kf + (size_t)BB * 128 * 512;
    float* qn2 = (float*)(Vf + (size_t)BB * 128 * 4 * 512);
    float* Mkb = qn2 + (size_t)BB * NN;

    proj_all_kernel<<<512, 256, 0, stream>>>(x, wq, bq, wk, bk, wv, bv,
                                             Qh, Kf, Vf, qn2, Mkb);
    attn_kernel<<<BB * 128, 256, 0, stream>>>(Qh, Kf, Vf, qn2, Mkb, x, gamma, out);
}